// Round 3
// baseline (8881.539 us; speedup 1.0000x reference)
//
#include <hip/hip_runtime.h>

// Problem constants (reference: B=8, L=1024, D=2048, H=512, OMEGA=5)
#define BB 8
#define LL 1024
#define DD 2048
#define HHH 512
#define OM 5
#define T_STEPS 1014            // L - 2*OMEGA
#define MROWS (BB * T_STEPS)    // 8112
#define SENT 0xFFFFFFFFu        // bf16 NaN|NaN — unreachable for finite h

typedef __bf16 bf16;
typedef bf16 bf16x8 __attribute__((ext_vector_type(8)));
typedef bf16 bf16x4 __attribute__((ext_vector_type(4)));
typedef float f32x4 __attribute__((ext_vector_type(4)));
typedef unsigned int u32;
typedef unsigned long long u64;
typedef u64 u64x2 __attribute__((ext_vector_type(2)));

__device__ __forceinline__ float sigm(float x) { return 1.0f / (1.0f + __expf(-x)); }
__device__ __forceinline__ float tanh_f(float x) { return 2.0f / (1.0f + __expf(-2.0f * x)) - 1.0f; }
__device__ __forceinline__ u32 bfbits(float x) {
    bf16 b = (bf16)x;
    unsigned short s = __builtin_bit_cast(unsigned short, b);
    return (u32)s;
}
__device__ __forceinline__ float bits2f(u32 v) {
    unsigned short s = (unsigned short)(v & 0xffffu);
    return (float)__builtin_bit_cast(bf16, s);
}
__device__ __forceinline__ u64 al64(const u64* p) {
    return __hip_atomic_load(p, __ATOMIC_RELAXED, __HIP_MEMORY_SCOPE_AGENT);
}
__device__ __forceinline__ bf16x8 quad2frag(u64 lo, u64 hi) {
    u64x2 t; t[0] = lo; t[1] = hi;
    return __builtin_bit_cast(bf16x8, t);
}
__device__ __forceinline__ bool quad_ok(u64 lo, u64 hi) {
    return ((u32)lo != SENT) & ((u32)(lo >> 32) != SENT) &
           ((u32)hi != SENT) & ((u32)(hi >> 32) != SENT);
}

#if defined(__has_builtin)
#if __has_builtin(__builtin_amdgcn_global_load_lds)
#define HAS_GLL 1
#endif
#endif
#ifndef HAS_GLL
#define HAS_GLL 0
#endif

#if HAS_GLL
__device__ __forceinline__ void llds16(const bf16* g, bf16* l) {
    __builtin_amdgcn_global_load_lds((const __attribute__((address_space(1))) void*)g,
                                     (__attribute__((address_space(3))) void*)l, 16, 0, 0);
}
#endif

// ---------------------------------------------------------------------------
// Prep kernels
// ---------------------------------------------------------------------------

__global__ void cast_x_kernel(const float* __restrict__ x, bf16* __restrict__ xb, int n4) {
    int i = blockIdx.x * 256 + threadIdx.x;
    if (i >= n4) return;
    float4 v = ((const float4*)x)[i];
    bf16x4 w = { (bf16)v.x, (bf16)v.y, (bf16)v.z, (bf16)v.w };
    *(bf16x4*)(xb + (long)i * 4) = w;
}

// Wdb/Wda: [H][D][5], Wr: [H][D][10]  ->  B^T layouts [H][K] with k = s*D + d
__global__ void prep_convw(const float* __restrict__ Wdb, const float* __restrict__ Wda,
                           const float* __restrict__ Wr,
                           bf16* __restrict__ Bdb, bf16* __restrict__ Bda, bf16* __restrict__ Br) {
    int idx = blockIdx.x * 256 + threadIdx.x;  // h*2048 + d
    if (idx >= HHH * DD) return;
    int h = idx >> 11, d = idx & 2047;
#pragma unroll
    for (int s = 0; s < 5; ++s) {
        Bdb[(long)h * 10240 + s * DD + d] = (bf16)Wdb[(long)(h * DD + d) * 5 + s];
        Bda[(long)h * 10240 + s * DD + d] = (bf16)Wda[(long)(h * DD + d) * 5 + s];
    }
#pragma unroll
    for (int s = 0; s < 10; ++s) {
        Br[(long)h * 20480 + s * DD + d] = (bf16)Wr[(long)(h * DD + d) * 10 + s];
    }
}

// Wihc: [4096][544]; output col c = dir*2048 + j*4 + g  <- Wih_dir row (g*512+j).
// K rows: 0..511 = Wih[:, :512]; 512 = hi(w512); 513 = hi(w512) (x vts_lo);
// 514 = lo(w512) (x vts_hi); 515 = bias (x 1.0); 516..543 = 0.
__global__ void prep_wihc(const float* __restrict__ Wih_fw, const float* __restrict__ bih_fw,
                          const float* __restrict__ bhh_fw,
                          const float* __restrict__ Wih_bw, const float* __restrict__ bih_bw,
                          const float* __restrict__ bhh_bw, bf16* __restrict__ Wihc) {
    int c = blockIdx.x;
    int tid = threadIdx.x;
    int dir = c >> 11;
    int jg = c & 2047;
    int j = jg >> 2, g = jg & 3;
    int row = g * 512 + j;
    const float* Wih = dir ? Wih_bw : Wih_fw;
    bf16* o = Wihc + (long)c * 544;
    for (int k = tid; k < 512; k += 256) o[k] = (bf16)Wih[(long)row * 513 + k];
    if (tid == 0) {
        float bias = dir ? (bih_bw[row] + bhh_bw[row]) : (bih_fw[row] + bhh_fw[row]);
        float w512 = Wih[(long)row * 513 + 512];
        bf16 hw = (bf16)w512;
        float lw = w512 - (float)hw;
        o[512] = hw; o[513] = hw; o[514] = (bf16)lw; o[515] = (bf16)bias;
    }
    if (tid >= 4 && tid < 32) o[512 + tid] = (bf16)0.0f;  // cols 516..543
}

// hist init: slot 0 = zeros (h_init), slots 1..T = SENT (un-written marker).
// Runs every call (harness re-poisons d_ws with 0xAA).
__global__ void init_kernel(u32* __restrict__ hf, u32* __restrict__ hb) {
    const long n4 = (long)(T_STEPS + 1) * 1024;  // uint4 count per dir
    long i = (long)blockIdx.x * 256 + threadIdx.x;
    if (i >= 2 * n4) return;
    u32* base = (i < n4) ? hf : hb;
    long k = (i < n4) ? i : (i - n4);
    u32 v = (k < 1024) ? 0u : SENT;  // first 1024 uint4 = slot 0
    uint4 val; val.x = v; val.y = v; val.z = v; val.w = v;
    ((uint4*)base)[k] = val;
}

// ---------------------------------------------------------------------------
// GEMM: C[M][*] = A_win/A_plain (bf16) @ B^T rows (bf16), fp32 accumulate.
// windowed: A row (b,t) = xb + (b*LL + t + shift)*DD  (contiguous im2col-free)
// cmode 0: fp32 store; cmode 1: bf16 store. cbias: per-output-col fp32 bias.
// Staging via global_load_lds width=16 (m97 pattern) when available.
// ---------------------------------------------------------------------------
__global__ __launch_bounds__(256, 2)
void gemm_bt(const bf16* __restrict__ A, const bf16* __restrict__ Bm, void* __restrict__ Cout,
             const float* __restrict__ cbias, int M, int K, int windowed, int shift,
             int lda, int ldc, int cmode) {
    __shared__ bf16 Ash[128 * 32];  // layout [koct][row][8]
    __shared__ bf16 Bsh[128 * 32];
    const int tid = threadIdx.x;
    const int m0 = blockIdx.x * 128;
    const int n0 = blockIdx.y * 128;

    long aoff[2], boff[2];
#pragma unroll
    for (int it = 0; it < 2; ++it) {
        int idx = it * 256 + tid;
        int r = idx & 127, koct = idx >> 7;
        int mg = m0 + r; if (mg >= M) mg = M - 1;
        long abase;
        if (windowed) {
            int b = mg / T_STEPS;
            int t = mg - b * T_STEPS;
            abase = ((long)(b * LL + t + shift)) * DD;
        } else {
            abase = (long)mg * lda;
        }
        aoff[it] = abase + koct * 8;
        boff[it] = (long)(n0 + r) * K + koct * 8;
    }

    const int wave = tid >> 6, lane = tid & 63;
    const int wr = (wave >> 1) * 64;
    const int wc = (wave & 1) * 64;
    const int q = lane >> 4, mm = lane & 15;

    f32x4 acc[4][4] = {};

    for (int k0 = 0; k0 < K; k0 += 32) {
#if HAS_GLL
        __syncthreads();  // protect LDS from overwrite while prior reads active
#pragma unroll
        for (int it = 0; it < 2; ++it) {
            // dst: lane writes (it*256 + wave*64 + lane)*16 bytes (HW: base+lane*16)
            bf16* la = Ash + (size_t)(it * 256 + wave * 64) * 8;
            bf16* lb = Bsh + (size_t)(it * 256 + wave * 64) * 8;
            llds16(A + aoff[it] + k0, la);
            llds16(Bm + boff[it] + k0, lb);
        }
        __syncthreads();  // compiler drains vmcnt(0) before barrier -> LDS ready
#else
        uint4 av[2], bv[2];
#pragma unroll
        for (int it = 0; it < 2; ++it) {
            av[it] = *(const uint4*)(A + aoff[it] + k0);
            bv[it] = *(const uint4*)(Bm + boff[it] + k0);
        }
        __syncthreads();
#pragma unroll
        for (int it = 0; it < 2; ++it) {
            int idx = it * 256 + tid;
            *(uint4*)((char*)Ash + idx * 16) = av[it];
            *(uint4*)((char*)Bsh + idx * 16) = bv[it];
        }
        __syncthreads();
#endif
        bf16x8 af[4], bfr[4];
#pragma unroll
        for (int i = 0; i < 4; ++i) {
            af[i]  = *(const bf16x8*)((char*)Ash + q * 2048 + (wr + i * 16 + mm) * 16);
            bfr[i] = *(const bf16x8*)((char*)Bsh + q * 2048 + (wc + i * 16 + mm) * 16);
        }
#pragma unroll
        for (int i = 0; i < 4; ++i)
#pragma unroll
            for (int j = 0; j < 4; ++j)
                acc[i][j] = __builtin_amdgcn_mfma_f32_16x16x32_bf16(af[i], bfr[j], acc[i][j], 0, 0, 0);
    }

#pragma unroll
    for (int i = 0; i < 4; ++i) {
        int rowb = m0 + wr + i * 16 + q * 4;
#pragma unroll
        for (int j = 0; j < 4; ++j) {
            int col = n0 + wc + j * 16 + mm;
            float bias = cbias ? cbias[col] : 0.0f;
#pragma unroll
            for (int r = 0; r < 4; ++r) {
                int gr = rowb + r;
                if (gr < M) {
                    float v = acc[i][j][r] + bias;
                    if (cmode == 0) ((float*)Cout)[(long)gr * ldc + col] = v;
                    else            ((bf16*)Cout)[(long)gr * ldc + col] = (bf16)v;
                }
            }
        }
    }
}

// ---------------------------------------------------------------------------
// vts_d[b,t] = dot(db[b,t,:], da[b,t,:]) -> joint cols 512..543 (hi/lo split + 1.0 + zeros)
// ---------------------------------------------------------------------------
__global__ void vts_kernel(const float* __restrict__ dbuf, const float* __restrict__ dabuf,
                           bf16* __restrict__ joint) {
    int gid = blockIdx.x * blockDim.x + threadIdx.x;
    int wid = gid >> 6, lane = gid & 63;
    if (wid >= MROWS) return;
    const float* p1 = dbuf + (long)wid * 512 + lane * 8;
    const float* p2 = dabuf + (long)wid * 512 + lane * 8;
    float s = 0.0f;
#pragma unroll
    for (int j = 0; j < 8; ++j) s += p1[j] * p2[j];
#pragma unroll
    for (int off = 32; off > 0; off >>= 1) s += __shfl_down(s, off);
    bf16* row = joint + (long)wid * 544;
    if (lane == 0) {
        bf16 hv = (bf16)s;
        float lo = s - (float)hv;
        row[512] = hv; row[513] = (bf16)lo; row[514] = hv; row[515] = (bf16)1.0f;
    }
    if (lane >= 4 && lane < 32) row[512 + lane] = (bf16)0.0f;  // cols 516..543
}

// ---------------------------------------------------------------------------
// Persistent LSTM, R9: 64 blocks x 64 threads; each wave owns 8 fw units AND
// 8 bw units (same j0) and INTERLEAVES the two independent recurrences.
// While fw's first-shot loads for step s+1 fly (issued right after the fw
// store), the wave runs the whole bw phase, and vice versa — each direction's
// store->IC->load RTT hides under the other direction's compute+poll.
// R8 evidence: poll traffic was ~139 B/wave/step (first-shot nearly always
// succeeds), so per-step time is pure serial latency; interleaving targets
// exactly that.
//
// SENTINEL DATAFLOW SYNC (unchanged): slots 1..T pre-filled 0xFFFFFFFF (bf16
// NaN pair, unreachable for finite h). Writers publish via relaxed agent u32
// stores; readers poll the data words themselves. Monotone => no deadlock:
// a wave polling dir-slot s has finished iteration s-1 entirely, so every
// input it needs was stored by waves at iteration >= its own.
//
// hist layout per dir (u32-packed, PERMUTED hidden axis): [T+1][16 b][256 u32]
// position p <-> unit (p&~7)+((p&7)>>1)+4*(p&1); same perm on Whh cols & Wfc.
// Reader quad (ks,q) covers exactly writer wave w=ks*4+q's 4 words.
// ---------------------------------------------------------------------------
__global__ __launch_bounds__(64) __attribute__((amdgpu_waves_per_eu(1, 1)))
void lstm_kernel(const float* __restrict__ Whh_fw, const float* __restrict__ Whh_bw,
                 const float* __restrict__ gih, u32* __restrict__ hist_fw,
                 u32* __restrict__ hist_bw) {
    const int w = blockIdx.x;   // 0..63
    const int j0 = w * 8;
    const int lane = threadIdx.x;
    const int q = lane >> 4, mm = lane & 15;
    const bool valid = (mm < 8);
    const int bcl = valid ? mm : 0;  // clamp gih row for pad lanes

    // Pre-pack A fragments for BOTH directions. Local rows rl = u*4+g
    // (u=unit, g=gate i/f/g/o); MFMA A layout: lane holds
    // A[m=lane&15][k=(lane>>4)*8+j]. Column j of k-octet (ks,q): permuted
    // position p=ks*32+q*8+j -> Whh column (p&~7)+(j>>1)+4*(j&1).
    bf16x8 afF[2][16], afB[2][16];
#pragma unroll
    for (int mt = 0; mt < 2; ++mt) {
        int rl = mt * 16 + mm;
        int u = rl >> 2, g = rl & 3;
        const float* wrF = Whh_fw + ((long)(g * 512 + j0 + u)) * 512;
        const float* wrB = Whh_bw + ((long)(g * 512 + j0 + u)) * 512;
#pragma unroll
        for (int ks = 0; ks < 16; ++ks) {
            int base = ks * 32 + q * 8;
            bf16x8 fF, fB;
#pragma unroll
            for (int j = 0; j < 8; ++j) {
                int col = base + (j >> 1) + ((j & 1) << 2);
                fF[j] = (bf16)wrF[col];
                fB[j] = (bf16)wrB[col];
            }
            afF[mt][ks] = fF;
            afB[mt][ks] = fB;
        }
    }

    float cF0 = 0.0f, cF1 = 0.0f, cB0 = 0.0f, cB1 = 0.0f;

    // gih prefetch for step 0 of each direction
    const float* gF0p = gih + ((long)(bcl * T_STEPS + 0)) * 4096 + (j0 + q) * 4;
    const float* gB0p = gih + ((long)(bcl * T_STEPS + (T_STEPS - 1))) * 4096 + 2048 + (j0 + q) * 4;
    f32x4 pgF0 = *(const f32x4*)gF0p, pgF1 = *(const f32x4*)(gF0p + 16);
    f32x4 pgB0 = *(const f32x4*)gB0p, pgB1 = *(const f32x4*)(gB0p + 16);

    u64 wvF[32], wvB[32];
#pragma unroll
    for (int i = 0; i < 32; ++i) { wvF[i] = 0ull; wvB[i] = 0ull; }
    u32 pF = 0u, pB = 0u;

    // prologue first-shots for slot 0 (slot 0 = zeros from init_kernel)
    if (valid) {
        const u64* hqF = (const u64*)(hist_fw + 0 + mm * 256);
        const u64* hqB = (const u64*)(hist_bw + 0 + mm * 256);
#pragma unroll
        for (int ks = 0; ks < 16; ++ks) {
            const u64* ppF = hqF + ks * 8 + q * 2;
            const u64* ppB = hqB + ks * 8 + q * 2;
            wvF[2 * ks] = al64(ppF + 0); wvF[2 * ks + 1] = al64(ppF + 1);
            wvB[2 * ks] = al64(ppB + 0); wvB[2 * ks + 1] = al64(ppB + 1);
        }
        pF = 0xFFFFu; pB = 0xFFFFu;
    }

    for (int s = 0; s < T_STEPS; ++s) {
        // ================= FW phase: consume slot s, produce slot s+1 =====
        {
            const u64* hq = (const u64*)(hist_fw + (long)s * 4096 + mm * 256);
            for (;;) {
#pragma unroll
                for (int ks = 0; ks < 16; ++ks)
                    if (pF & (1u << ks))
                        if (quad_ok(wvF[2 * ks], wvF[2 * ks + 1])) pF &= ~(1u << ks);
                if (__all((int)(pF == 0u))) break;
                __builtin_amdgcn_s_sleep(1);
#pragma unroll
                for (int ks = 0; ks < 16; ++ks)
                    if (pF & (1u << ks)) {
                        const u64* pp = hq + ks * 8 + q * 2;
                        wvF[2 * ks]     = al64(pp + 0);
                        wvF[2 * ks + 1] = al64(pp + 1);
                    }
            }

            f32x4 a0 = pgF0, a1 = pgF1;
            f32x4 b0 = {0.0f, 0.0f, 0.0f, 0.0f}, b1 = {0.0f, 0.0f, 0.0f, 0.0f};

            if (s + 1 < T_STEPS) {
                const float* gpn = gih + ((long)(bcl * T_STEPS + (s + 1))) * 4096 + (j0 + q) * 4;
                pgF0 = *(const f32x4*)gpn;
                pgF1 = *(const f32x4*)(gpn + 16);
            }

#pragma unroll
            for (int ks = 0; ks < 8; ++ks) {
                bf16x8 blo = quad2frag(wvF[2 * ks], wvF[2 * ks + 1]);
                bf16x8 bhi = quad2frag(wvF[2 * (ks + 8)], wvF[2 * (ks + 8) + 1]);
                a0 = __builtin_amdgcn_mfma_f32_16x16x32_bf16(afF[0][ks], blo, a0, 0, 0, 0);
                a1 = __builtin_amdgcn_mfma_f32_16x16x32_bf16(afF[1][ks], blo, a1, 0, 0, 0);
                b0 = __builtin_amdgcn_mfma_f32_16x16x32_bf16(afF[0][ks + 8], bhi, b0, 0, 0, 0);
                b1 = __builtin_amdgcn_mfma_f32_16x16x32_bf16(afF[1][ks + 8], bhi, b1, 0, 0, 0);
            }
            a0 += b0; a1 += b1;

            float ig = sigm(a0[0]), fg = sigm(a0[1]), gg = tanh_f(a0[2]), og = sigm(a0[3]);
            cF0 = fg * cF0 + ig * gg;
            float h0 = og * tanh_f(cF0);
            ig = sigm(a1[0]); fg = sigm(a1[1]); gg = tanh_f(a1[2]); og = sigm(a1[3]);
            cF1 = fg * cF1 + ig * gg;
            float h1 = og * tanh_f(cF1);

            if (valid) {
                u32 pw = bfbits(h0) | (bfbits(h1) << 16);
                __hip_atomic_store(hist_fw + (long)(s + 1) * 4096 + mm * 256 + (j0 >> 1) + q, pw,
                                   __ATOMIC_RELAXED, __HIP_MEMORY_SCOPE_AGENT);
            }

            // first-shot for fw slot s+1: flies while the BW phase runs
            if (s + 1 < T_STEPS && valid) {
                const u64* hqn = (const u64*)(hist_fw + (long)(s + 1) * 4096 + mm * 256);
#pragma unroll
                for (int ks = 0; ks < 16; ++ks) {
                    const u64* pp = hqn + ks * 8 + q * 2;
                    wvF[2 * ks]     = al64(pp + 0);
                    wvF[2 * ks + 1] = al64(pp + 1);
                }
                pF = 0xFFFFu;
            }
        }

        // ================= BW phase: consume slot s, produce slot s+1 =====
        {
            const u64* hq = (const u64*)(hist_bw + (long)s * 4096 + mm * 256);
            for (;;) {
#pragma unroll
                for (int ks = 0; ks < 16; ++ks)
                    if (pB & (1u << ks))
                        if (quad_ok(wvB[2 * ks], wvB[2 * ks + 1])) pB &= ~(1u << ks);
                if (__all((int)(pB == 0u))) break;
                __builtin_amdgcn_s_sleep(1);
#pragma unroll
                for (int ks = 0; ks < 16; ++ks)
                    if (pB & (1u << ks)) {
                        const u64* pp = hq + ks * 8 + q * 2;
                        wvB[2 * ks]     = al64(pp + 0);
                        wvB[2 * ks + 1] = al64(pp + 1);
                    }
            }

            f32x4 a0 = pgB0, a1 = pgB1;
            f32x4 b0 = {0.0f, 0.0f, 0.0f, 0.0f}, b1 = {0.0f, 0.0f, 0.0f, 0.0f};

            if (s + 1 < T_STEPS) {
                const float* gpn = gih + ((long)(bcl * T_STEPS + (T_STEPS - 2 - s))) * 4096 + 2048 + (j0 + q) * 4;
                pgB0 = *(const f32x4*)gpn;
                pgB1 = *(const f32x4*)(gpn + 16);
            }

#pragma unroll
            for (int ks = 0; ks < 8; ++ks) {
                bf16x8 blo = quad2frag(wvB[2 * ks], wvB[2 * ks + 1]);
                bf16x8 bhi = quad2frag(wvB[2 * (ks + 8)], wvB[2 * (ks + 8) + 1]);
                a0 = __builtin_amdgcn_mfma_f32_16x16x32_bf16(afB[0][ks], blo, a0, 0, 0, 0);
                a1 = __builtin_amdgcn_mfma_f32_16x16x32_bf16(afB[1][ks], blo, a1, 0, 0, 0);
                b0 = __builtin_amdgcn_mfma_f32_16x16x32_bf16(afB[0][ks + 8], bhi, b0, 0, 0, 0);
                b1 = __builtin_amdgcn_mfma_f32_16x16x32_bf16(afB[1][ks + 8], bhi, b1, 0, 0, 0);
            }
            a0 += b0; a1 += b1;

            float ig = sigm(a0[0]), fg = sigm(a0[1]), gg = tanh_f(a0[2]), og = sigm(a0[3]);
            cB0 = fg * cB0 + ig * gg;
            float h0 = og * tanh_f(cB0);
            ig = sigm(a1[0]); fg = sigm(a1[1]); gg = tanh_f(a1[2]); og = sigm(a1[3]);
            cB1 = fg * cB1 + ig * gg;
            float h1 = og * tanh_f(cB1);

            if (valid) {
                u32 pw = bfbits(h0) | (bfbits(h1) << 16);
                __hip_atomic_store(hist_bw + (long)(s + 1) * 4096 + mm * 256 + (j0 >> 1) + q, pw,
                                   __ATOMIC_RELAXED, __HIP_MEMORY_SCOPE_AGENT);
            }

            // first-shot for bw slot s+1: flies while the next FW phase runs
            if (s + 1 < T_STEPS && valid) {
                const u64* hqn = (const u64*)(hist_bw + (long)(s + 1) * 4096 + mm * 256);
#pragma unroll
                for (int ks = 0; ks < 16; ++ks) {
                    const u64* pp = hqn + ks * 8 + q * 2;
                    wvB[2 * ks]     = al64(pp + 0);
                    wvB[2 * ks + 1] = al64(pp + 1);
                }
                pB = 0xFFFFu;
            }
        }
    }
}

// ---------------------------------------------------------------------------
// out[b*T+t] = sigmoid(h_fw[t] . Wfc[:512] + h_bw[t] . Wfc[512:] + bfc)
// hist is u32-packed with the permuted hidden axis: lane reads words
// lane*4 .. +4: word i -> units 8*lane+i (lo16) and 8*lane+4+i (hi16).
// ---------------------------------------------------------------------------
__global__ void final_fc(const u32* __restrict__ hist_fw, const u32* __restrict__ hist_bw,
                         const float* __restrict__ Wfc, const float* __restrict__ bfc,
                         float* __restrict__ out) {
    int gid = blockIdx.x * blockDim.x + threadIdx.x;
    int wid = gid >> 6, lane = gid & 63;
    if (wid >= MROWS) return;
    int b = wid / T_STEPS, t = wid - b * T_STEPS;
    const u32* hf = hist_fw + (long)(t + 1) * 4096 + b * 256 + lane * 4;
    const u32* hb = hist_bw + (long)(T_STEPS - t) * 4096 + b * 256 + lane * 4;
    float s = 0.0f;
#pragma unroll
    for (int i = 0; i < 4; ++i) {
        u32 wf = hf[i], wb = hb[i];
        s += bits2f(wf) * Wfc[8 * lane + i] + bits2f(wf >> 16) * Wfc[8 * lane + 4 + i];
        s += bits2f(wb) * Wfc[512 + 8 * lane + i] + bits2f(wb >> 16) * Wfc[512 + 8 * lane + 4 + i];
    }
#pragma unroll
    for (int off = 32; off > 0; off >>= 1) s += __shfl_down(s, off);
    if (lane == 0) out[wid] = 1.0f / (1.0f + __expf(-(s + bfc[0])));
}

// ---------------------------------------------------------------------------

extern "C" void kernel_launch(void* const* d_in, const int* in_sizes, int n_in,
                              void* d_out, int out_size, void* d_ws, size_t ws_size,
                              hipStream_t stream) {
    const float* x      = (const float*)d_in[0];
    const float* Wdb    = (const float*)d_in[1];
    const float* bdb    = (const float*)d_in[2];
    const float* Wda    = (const float*)d_in[3];
    const float* bda    = (const float*)d_in[4];
    const float* Wr     = (const float*)d_in[5];
    const float* br     = (const float*)d_in[6];
    const float* Wih_fw = (const float*)d_in[7];
    const float* Whh_fw = (const float*)d_in[8];
    const float* bih_fw = (const float*)d_in[9];
    const float* bhh_fw = (const float*)d_in[10];
    const float* Wih_bw = (const float*)d_in[11];
    const float* Whh_bw = (const float*)d_in[12];
    const float* bih_bw = (const float*)d_in[13];
    const float* bhh_bw = (const float*)d_in[14];
    const float* Wfc    = (const float*)d_in[15];
    const float* bfc    = (const float*)d_in[16];
    float* out = (float*)d_out;

    // ---- workspace layout with aliasing (peak ~179.5 MB) ----
    char* p = (char*)d_ws;
    auto alloc = [&](size_t bytes) { char* r = p; p += (bytes + 255) & ~(size_t)255; return r; };
    // persistent region (~46.6 MB): alive until the end
    bf16* Wihc    = (bf16*)alloc((size_t)4096 * 544 * 2);            // 4.5 MB
    bf16* joint   = (bf16*)alloc((size_t)MROWS * 544 * 2);           // 8.8 MB
    u32* hist_fw  = (u32*)alloc((size_t)(T_STEPS + 1) * 4096 * 4);   // 16.6 MB
    u32* hist_bw  = (u32*)alloc((size_t)(T_STEPS + 1) * 4096 * 4);   // 16.6 MB
    // overlay region Q: phase-1 conv buffers, later overwritten by gih
    char* q0 = p;
    bf16* xb      = (bf16*)alloc((size_t)BB * LL * DD * 2);          // 33.6 MB
    bf16* Bdb     = (bf16*)alloc((size_t)512 * 10240 * 2);           // 10.5 MB
    bf16* Bda     = (bf16*)alloc((size_t)512 * 10240 * 2);           // 10.5 MB
    bf16* Br      = (bf16*)alloc((size_t)512 * 20480 * 2);           // 21.0 MB
    float* dbuf   = (float*)alloc((size_t)MROWS * 512 * 4);          // 16.6 MB
    float* dabuf  = (float*)alloc((size_t)MROWS * 512 * 4);          // 16.6 MB
    float* gih    = (float*)q0;  // 132.9 MB, overwrites all of the above
    (void)ws_size;

    cast_x_kernel<<<16384, 256, 0, stream>>>(x, xb, BB * LL * DD / 4);
    prep_convw<<<4096, 256, 0, stream>>>(Wdb, Wda, Wr, Bdb, Bda, Br);
    prep_wihc<<<4096, 256, 0, stream>>>(Wih_fw, bih_fw, bhh_fw, Wih_bw, bih_bw, bhh_bw, Wihc);
    {
        long n4 = (long)(T_STEPS + 1) * 1024 * 2;
        init_kernel<<<(int)((n4 + 255) / 256), 256, 0, stream>>>(hist_fw, hist_bw);
    }

    dim3 g1(64, 4);
    // db: window [t, t+5);  da: window [t+5, t+10);  r: window [t, t+10)
    gemm_bt<<<g1, 256, 0, stream>>>(xb, Bdb, dbuf, bdb, MROWS, 10240, 1, 0, 0, 512, 0);
    gemm_bt<<<g1, 256, 0, stream>>>(xb, Bda, dabuf, bda, MROWS, 10240, 1, 5, 0, 512, 0);
    gemm_bt<<<g1, 256, 0, stream>>>(xb, Br, joint, br, MROWS, 20480, 1, 0, 0, 544, 1);
    vts_kernel<<<(MROWS * 64 + 255) / 256, 256, 0, stream>>>(dbuf, dabuf, joint);

    // gih GEMM: reads only joint + Wihc; writes gih over the dead conv buffers
    dim3 g2(64, 32);
    gemm_bt<<<g2, 256, 0, stream>>>(joint, Wihc, gih, nullptr, MROWS, 544, 0, 0, 544, 4096, 0);

    lstm_kernel<<<dim3(64), dim3(64), 0, stream>>>(Whh_fw, Whh_bw, gih, hist_fw, hist_bw);

    final_fc<<<(MROWS * 64 + 255) / 256, 256, 0, stream>>>(hist_fw, hist_bw, Wfc, bfc, out);
}

// Round 4
// 4902.968 us; speedup vs baseline: 1.8115x; 1.8115x over previous
//
#include <hip/hip_runtime.h>

// Problem constants (reference: B=8, L=1024, D=2048, H=512, OMEGA=5)
#define BB 8
#define LL 1024
#define DD 2048
#define HHH 512
#define OM 5
#define T_STEPS 1014            // L - 2*OMEGA
#define MROWS (BB * T_STEPS)    // 8112
#define SENT 0xFFFFFFFFu        // bf16 NaN|NaN — unreachable for finite h

typedef __bf16 bf16;
typedef bf16 bf16x8 __attribute__((ext_vector_type(8)));
typedef bf16 bf16x4 __attribute__((ext_vector_type(4)));
typedef float f32x4 __attribute__((ext_vector_type(4)));
typedef unsigned int u32;
typedef unsigned long long u64;
typedef u64 u64x2 __attribute__((ext_vector_type(2)));

__device__ __forceinline__ float sigm(float x) { return 1.0f / (1.0f + __expf(-x)); }
__device__ __forceinline__ float tanh_f(float x) { return 2.0f / (1.0f + __expf(-2.0f * x)) - 1.0f; }
__device__ __forceinline__ u32 bfbits(float x) {
    bf16 b = (bf16)x;
    unsigned short s = __builtin_bit_cast(unsigned short, b);
    return (u32)s;
}
__device__ __forceinline__ float bits2f(u32 v) {
    unsigned short s = (unsigned short)(v & 0xffffu);
    return (float)__builtin_bit_cast(bf16, s);
}
__device__ __forceinline__ u64 al64(const u64* p) {
    return __hip_atomic_load(p, __ATOMIC_RELAXED, __HIP_MEMORY_SCOPE_AGENT);
}
__device__ __forceinline__ bf16x8 quad2frag(u64 lo, u64 hi) {
    u64x2 t; t[0] = lo; t[1] = hi;
    return __builtin_bit_cast(bf16x8, t);
}
__device__ __forceinline__ bool quad_ok(u64 lo, u64 hi) {
    return ((u32)lo != SENT) & ((u32)(lo >> 32) != SENT) &
           ((u32)hi != SENT) & ((u32)(hi >> 32) != SENT);
}

#if defined(__has_builtin)
#if __has_builtin(__builtin_amdgcn_global_load_lds)
#define HAS_GLL 1
#endif
#endif
#ifndef HAS_GLL
#define HAS_GLL 0
#endif

#if HAS_GLL
__device__ __forceinline__ void llds16(const bf16* g, bf16* l) {
    __builtin_amdgcn_global_load_lds((const __attribute__((address_space(1))) void*)g,
                                     (__attribute__((address_space(3))) void*)l, 16, 0, 0);
}
#endif

// ---------------------------------------------------------------------------
// Prep kernels
// ---------------------------------------------------------------------------

__global__ void cast_x_kernel(const float* __restrict__ x, bf16* __restrict__ xb, int n4) {
    int i = blockIdx.x * 256 + threadIdx.x;
    if (i >= n4) return;
    float4 v = ((const float4*)x)[i];
    bf16x4 w = { (bf16)v.x, (bf16)v.y, (bf16)v.z, (bf16)v.w };
    *(bf16x4*)(xb + (long)i * 4) = w;
}

// Wdb/Wda: [H][D][5], Wr: [H][D][10]  ->  B^T layouts [H][K] with k = s*D + d
__global__ void prep_convw(const float* __restrict__ Wdb, const float* __restrict__ Wda,
                           const float* __restrict__ Wr,
                           bf16* __restrict__ Bdb, bf16* __restrict__ Bda, bf16* __restrict__ Br) {
    int idx = blockIdx.x * 256 + threadIdx.x;  // h*2048 + d
    if (idx >= HHH * DD) return;
    int h = idx >> 11, d = idx & 2047;
#pragma unroll
    for (int s = 0; s < 5; ++s) {
        Bdb[(long)h * 10240 + s * DD + d] = (bf16)Wdb[(long)(h * DD + d) * 5 + s];
        Bda[(long)h * 10240 + s * DD + d] = (bf16)Wda[(long)(h * DD + d) * 5 + s];
    }
#pragma unroll
    for (int s = 0; s < 10; ++s) {
        Br[(long)h * 20480 + s * DD + d] = (bf16)Wr[(long)(h * DD + d) * 10 + s];
    }
}

// Wihc: [4096][544]; output col c = dir*2048 + j*4 + g  <- Wih_dir row (g*512+j).
// K rows: 0..511 = Wih[:, :512]; 512 = hi(w512); 513 = hi(w512) (x vts_lo);
// 514 = lo(w512) (x vts_hi); 515 = bias (x 1.0); 516..543 = 0.
__global__ void prep_wihc(const float* __restrict__ Wih_fw, const float* __restrict__ bih_fw,
                          const float* __restrict__ bhh_fw,
                          const float* __restrict__ Wih_bw, const float* __restrict__ bih_bw,
                          const float* __restrict__ bhh_bw, bf16* __restrict__ Wihc) {
    int c = blockIdx.x;
    int tid = threadIdx.x;
    int dir = c >> 11;
    int jg = c & 2047;
    int j = jg >> 2, g = jg & 3;
    int row = g * 512 + j;
    const float* Wih = dir ? Wih_bw : Wih_fw;
    bf16* o = Wihc + (long)c * 544;
    for (int k = tid; k < 512; k += 256) o[k] = (bf16)Wih[(long)row * 513 + k];
    if (tid == 0) {
        float bias = dir ? (bih_bw[row] + bhh_bw[row]) : (bih_fw[row] + bhh_fw[row]);
        float w512 = Wih[(long)row * 513 + 512];
        bf16 hw = (bf16)w512;
        float lw = w512 - (float)hw;
        o[512] = hw; o[513] = hw; o[514] = (bf16)lw; o[515] = (bf16)bias;
    }
    if (tid >= 4 && tid < 32) o[512 + tid] = (bf16)0.0f;  // cols 516..543
}

// hist init: slot 0 = zeros (h_init), slots 1..T = SENT (un-written marker).
// Runs every call (harness re-poisons d_ws with 0xAA).
__global__ void init_kernel(u32* __restrict__ hf, u32* __restrict__ hb) {
    const long n4 = (long)(T_STEPS + 1) * 1024;  // uint4 count per dir
    long i = (long)blockIdx.x * 256 + threadIdx.x;
    if (i >= 2 * n4) return;
    u32* base = (i < n4) ? hf : hb;
    long k = (i < n4) ? i : (i - n4);
    u32 v = (k < 1024) ? 0u : SENT;  // first 1024 uint4 = slot 0
    uint4 val; val.x = v; val.y = v; val.z = v; val.w = v;
    ((uint4*)base)[k] = val;
}

// ---------------------------------------------------------------------------
// GEMM core: C[M][*] = A_win/A_plain (bf16) @ B^T rows (bf16), fp32 accumulate.
// windowed: A row (b,t) = xb + (b*LL + t + shift)*DD  (contiguous im2col-free)
// cmode 0: fp32 store; cmode 1: bf16 store. cbias: per-output-col fp32 bias.
// Staging via global_load_lds width=16 (m97 pattern) when available.
// Shared-memory buffers passed in so multi-branch wrappers keep ONE allocation.
// ---------------------------------------------------------------------------
__device__ __forceinline__
void gemm_core(bf16* Ash, bf16* Bsh,
               const bf16* __restrict__ A, const bf16* __restrict__ Bm, void* __restrict__ Cout,
               const float* __restrict__ cbias, int M, int K, int windowed, int shift,
               int lda, int ldc, int cmode) {
    const int tid = threadIdx.x;
    const int m0 = blockIdx.x * 128;
    const int n0 = blockIdx.y * 128;

    long aoff[2], boff[2];
#pragma unroll
    for (int it = 0; it < 2; ++it) {
        int idx = it * 256 + tid;
        int r = idx & 127, koct = idx >> 7;
        int mg = m0 + r; if (mg >= M) mg = M - 1;
        long abase;
        if (windowed) {
            int b = mg / T_STEPS;
            int t = mg - b * T_STEPS;
            abase = ((long)(b * LL + t + shift)) * DD;
        } else {
            abase = (long)mg * lda;
        }
        aoff[it] = abase + koct * 8;
        boff[it] = (long)(n0 + r) * K + koct * 8;
    }

    const int wave = tid >> 6, lane = tid & 63;
    const int wr = (wave >> 1) * 64;
    const int wc = (wave & 1) * 64;
    const int q = lane >> 4, mm = lane & 15;

    f32x4 acc[4][4] = {};

    for (int k0 = 0; k0 < K; k0 += 32) {
#if HAS_GLL
        __syncthreads();  // protect LDS from overwrite while prior reads active
#pragma unroll
        for (int it = 0; it < 2; ++it) {
            // dst: lane writes (it*256 + wave*64 + lane)*16 bytes (HW: base+lane*16)
            bf16* la = Ash + (size_t)(it * 256 + wave * 64) * 8;
            bf16* lb = Bsh + (size_t)(it * 256 + wave * 64) * 8;
            llds16(A + aoff[it] + k0, la);
            llds16(Bm + boff[it] + k0, lb);
        }
        __syncthreads();  // compiler drains vmcnt(0) before barrier -> LDS ready
#else
        uint4 av[2], bv[2];
#pragma unroll
        for (int it = 0; it < 2; ++it) {
            av[it] = *(const uint4*)(A + aoff[it] + k0);
            bv[it] = *(const uint4*)(Bm + boff[it] + k0);
        }
        __syncthreads();
#pragma unroll
        for (int it = 0; it < 2; ++it) {
            int idx = it * 256 + tid;
            *(uint4*)((char*)Ash + idx * 16) = av[it];
            *(uint4*)((char*)Bsh + idx * 16) = bv[it];
        }
        __syncthreads();
#endif
        bf16x8 af[4], bfr[4];
#pragma unroll
        for (int i = 0; i < 4; ++i) {
            af[i]  = *(const bf16x8*)((char*)Ash + q * 2048 + (wr + i * 16 + mm) * 16);
            bfr[i] = *(const bf16x8*)((char*)Bsh + q * 2048 + (wc + i * 16 + mm) * 16);
        }
#pragma unroll
        for (int i = 0; i < 4; ++i)
#pragma unroll
            for (int j = 0; j < 4; ++j)
                acc[i][j] = __builtin_amdgcn_mfma_f32_16x16x32_bf16(af[i], bfr[j], acc[i][j], 0, 0, 0);
    }

#pragma unroll
    for (int i = 0; i < 4; ++i) {
        int rowb = m0 + wr + i * 16 + q * 4;
#pragma unroll
        for (int j = 0; j < 4; ++j) {
            int col = n0 + wc + j * 16 + mm;
            float bias = cbias ? cbias[col] : 0.0f;
#pragma unroll
            for (int r = 0; r < 4; ++r) {
                int gr = rowb + r;
                if (gr < M) {
                    float v = acc[i][j][r] + bias;
                    if (cmode == 0) ((float*)Cout)[(long)gr * ldc + col] = v;
                    else            ((bf16*)Cout)[(long)gr * ldc + col] = (bf16)v;
                }
            }
        }
    }
}

__global__ __launch_bounds__(256, 2)
void gemm_bt(const bf16* __restrict__ A, const bf16* __restrict__ Bm, void* __restrict__ Cout,
             const float* __restrict__ cbias, int M, int K, int windowed, int shift,
             int lda, int ldc, int cmode) {
    __shared__ bf16 Ash[128 * 32];
    __shared__ bf16 Bsh[128 * 32];
    gemm_core(Ash, Bsh, A, Bm, Cout, cbias, M, K, windowed, shift, lda, ldc, cmode);
}

// db + da conv GEMMs fused into one 512-block launch (blockIdx.z selects):
// 2 blocks/CU restores the implicit inter-block staging/compute overlap that
// the 256-block separate launches (1 block/CU) lacked.
__global__ __launch_bounds__(256, 2)
void gemm_bt_dd(const bf16* __restrict__ A, const bf16* __restrict__ B0,
                const bf16* __restrict__ B1, float* __restrict__ C0, float* __restrict__ C1,
                const float* __restrict__ bias0, const float* __restrict__ bias1) {
    __shared__ bf16 Ash[128 * 32];
    __shared__ bf16 Bsh[128 * 32];
    if (blockIdx.z == 0)
        gemm_core(Ash, Bsh, A, B0, C0, bias0, MROWS, 10240, 1, 0, 0, 512, 0);
    else
        gemm_core(Ash, Bsh, A, B1, C1, bias1, MROWS, 10240, 1, 5, 0, 512, 0);
}

// ---------------------------------------------------------------------------
// vts_d[b,t] = dot(db[b,t,:], da[b,t,:]) -> joint cols 512..543 (hi/lo split + 1.0 + zeros)
// ---------------------------------------------------------------------------
__global__ void vts_kernel(const float* __restrict__ dbuf, const float* __restrict__ dabuf,
                           bf16* __restrict__ joint) {
    int gid = blockIdx.x * blockDim.x + threadIdx.x;
    int wid = gid >> 6, lane = gid & 63;
    if (wid >= MROWS) return;
    const float* p1 = dbuf + (long)wid * 512 + lane * 8;
    const float* p2 = dabuf + (long)wid * 512 + lane * 8;
    float s = 0.0f;
#pragma unroll
    for (int j = 0; j < 8; ++j) s += p1[j] * p2[j];
#pragma unroll
    for (int off = 32; off > 0; off >>= 1) s += __shfl_down(s, off);
    bf16* row = joint + (long)wid * 544;
    if (lane == 0) {
        bf16 hv = (bf16)s;
        float lo = s - (float)hv;
        row[512] = hv; row[513] = (bf16)lo; row[514] = hv; row[515] = (bf16)1.0f;
    }
    if (lane >= 4 && lane < 32) row[512 + lane] = (bf16)0.0f;  // cols 516..543
}

// ---------------------------------------------------------------------------
// Persistent LSTM (R8 topology, R10 poll): 128 blocks x 64 threads
// (64 waves/dir, 8 hidden units per wave). Plain launch: 128 one-wave WGs on
// an idle 256-CU GPU => co-resident; dataflow sync can't deadlock (monotone).
//
// SENTINEL DATAFLOW SYNC: slots 1..T pre-filled with 0xFFFFFFFF (bf16 NaN
// pair — finite h never produces it). Writers publish h via relaxed agent
// u32 stores; readers poll the h words themselves until != SENT.
//
// R10 vs R8: the poll loops spin WITHOUT s_sleep. R8 counters showed poll
// traffic ~139 B/wave/step (first-shot nearly always succeeds) => per-step
// time is latency-quantized, not contention-bound. Removing the 64cy sleep
// shrinks the retry quantum and keeps the wave issuing ops (DVFS-friendly).
// Narrowing pend-mask keeps reload traffic bounded.
//
// hist layout per dir (u32-packed, PERMUTED hidden axis): [T+1][16 b][256 u32]
// position p <-> unit (p&~7)+((p&7)>>1)+4*(p&1); same perm on Whh cols & Wfc.
// ---------------------------------------------------------------------------
__global__ __launch_bounds__(64) __attribute__((amdgpu_waves_per_eu(1, 1)))
void lstm_kernel(const float* __restrict__ Whh_fw, const float* __restrict__ Whh_bw,
                 const float* __restrict__ gih, u32* __restrict__ hist_fw,
                 u32* __restrict__ hist_bw) {
    const int wgid = blockIdx.x;
    const int dir = wgid >> 6;
    const int w = wgid & 63;
    const int j0 = w * 8;
    const int lane = threadIdx.x;
    const float* Whh = dir ? Whh_bw : Whh_fw;
    u32* hist = dir ? hist_bw : hist_fw;

    const int q = lane >> 4, mm = lane & 15;

    // Pre-pack A fragments: local rows rl = u*4+g (u=unit, g=gate i/f/g/o),
    // MFMA A layout: lane holds A[m=lane&15][k=(lane>>4)*8 + j].
    // Column j of k-octet (ks,q): permuted position p=ks*32+q*8+j
    // -> Whh column (p&~7) + (j>>1) + 4*(j&1).
    bf16x8 afrag[2][16];
#pragma unroll
    for (int mt = 0; mt < 2; ++mt) {
        int rl = mt * 16 + mm;
        int u = rl >> 2, g = rl & 3;
        const float* wrow = Whh + ((long)(g * 512 + j0 + u)) * 512;
#pragma unroll
        for (int ks = 0; ks < 16; ++ks) {
            int base = ks * 32 + q * 8;
            bf16x8 f;
#pragma unroll
            for (int j = 0; j < 8; ++j) {
                int col = base + (j >> 1) + ((j & 1) << 2);
                f[j] = (bf16)wrow[col];
            }
            afrag[mt][ks] = f;
        }
    }

    float c0 = 0.0f, c1 = 0.0f;
    const bool valid = (mm < 8);
    const int bcl = valid ? mm : 0;  // clamp gih row for pad lanes

    int tcur = dir ? (T_STEPS - 1) : 0;
    const float* gp0 = gih + ((long)(bcl * T_STEPS + tcur)) * 4096 + dir * 2048 + (j0 + q) * 4;
    f32x4 pg0 = *(const f32x4*)gp0;
    f32x4 pg1 = *(const f32x4*)(gp0 + 16);

    for (int s = 0; s < T_STEPS; ++s) {
        const u64* hrow = (const u64*)(hist + (long)s * 4096 + mm * 256);
        // quad ks lives at u64 indices ks*8 + q*2 + {0,1}
        u64 wa[16], wb[16];
#pragma unroll
        for (int i = 0; i < 16; ++i) { wa[i] = 0ull; wb[i] = 0ull; }

        // ---- half 0 (quads 0..7): first-shot issue, then tight spin ----
        u32 pa = valid ? 0xFFu : 0u;
        if (valid) {
#pragma unroll
            for (int ks = 0; ks < 8; ++ks) {
                const u64* p = hrow + ks * 8 + q * 2;
                wa[2 * ks]     = al64(p + 0);
                wa[2 * ks + 1] = al64(p + 1);
            }
        }
        for (;;) {
#pragma unroll
            for (int ks = 0; ks < 8; ++ks) {
                if (pa & (1u << ks)) {
                    if (quad_ok(wa[2 * ks], wa[2 * ks + 1])) pa &= ~(1u << ks);
                }
            }
            if (__all((int)(pa == 0u))) break;
#pragma unroll
            for (int ks = 0; ks < 8; ++ks) {
                if (pa & (1u << ks)) {
                    const u64* p = hrow + ks * 8 + q * 2;
                    wa[2 * ks]     = al64(p + 0);
                    wa[2 * ks + 1] = al64(p + 1);
                }
            }
        }

        // ---- first-shot issue of half 1 (overlaps with half-0 MFMAs) ----
        u32 pb = valid ? 0xFFu : 0u;
        if (valid) {
#pragma unroll
            for (int ks = 0; ks < 8; ++ks) {
                const u64* p = hrow + (ks + 8) * 8 + q * 2;
                wb[2 * ks]     = al64(p + 0);
                wb[2 * ks + 1] = al64(p + 1);
            }
        }

        // C operand = precomputed input gates (bias included, (j*4+g) order)
        f32x4 acc0 = pg0, acc1 = pg1;
        f32x4 acc0b = {0.0f, 0.0f, 0.0f, 0.0f}, acc1b = {0.0f, 0.0f, 0.0f, 0.0f};

        // prefetch gih for next step (hides under the MFMA chain)
        if (s + 1 < T_STEPS) {
            int tn = dir ? (T_STEPS - 2 - s) : (s + 1);
            const float* gpn = gih + ((long)(bcl * T_STEPS + tn)) * 4096 + dir * 2048 + (j0 + q) * 4;
            pg0 = *(const f32x4*)gpn;
            pg1 = *(const f32x4*)(gpn + 16);
        }

        // ---- MFMA half 0 (half-1 loads in flight) ----
#pragma unroll
        for (int ks = 0; ks < 8; ++ks) {
            bf16x8 b = quad2frag(wa[2 * ks], wa[2 * ks + 1]);
            acc0 = __builtin_amdgcn_mfma_f32_16x16x32_bf16(afrag[0][ks], b, acc0, 0, 0, 0);
            acc1 = __builtin_amdgcn_mfma_f32_16x16x32_bf16(afrag[1][ks], b, acc1, 0, 0, 0);
        }

        // ---- finish poll half 1 (tight spin) ----
        for (;;) {
#pragma unroll
            for (int ks = 0; ks < 8; ++ks) {
                if (pb & (1u << ks)) {
                    if (quad_ok(wb[2 * ks], wb[2 * ks + 1])) pb &= ~(1u << ks);
                }
            }
            if (__all((int)(pb == 0u))) break;
#pragma unroll
            for (int ks = 0; ks < 8; ++ks) {
                if (pb & (1u << ks)) {
                    const u64* p = hrow + (ks + 8) * 8 + q * 2;
                    wb[2 * ks]     = al64(p + 0);
                    wb[2 * ks + 1] = al64(p + 1);
                }
            }
        }

        // ---- MFMA half 1 ----
#pragma unroll
        for (int ks = 0; ks < 8; ++ks) {
            bf16x8 b = quad2frag(wb[2 * ks], wb[2 * ks + 1]);
            acc0b = __builtin_amdgcn_mfma_f32_16x16x32_bf16(afrag[0][ks + 8], b, acc0b, 0, 0, 0);
            acc1b = __builtin_amdgcn_mfma_f32_16x16x32_bf16(afrag[1][ks + 8], b, acc1b, 0, 0, 0);
        }
        acc0 += acc0b;
        acc1 += acc1b;

        // D layout: col=lane&15=b, row=(lane>>4)*4+reg -> unit q (+4), gate = reg
        float ig = sigm(acc0[0]), fg = sigm(acc0[1]), gg = tanh_f(acc0[2]), og = sigm(acc0[3]);
        c0 = fg * c0 + ig * gg;
        float h0 = og * tanh_f(c0);
        ig = sigm(acc1[0]); fg = sigm(acc1[1]); gg = tanh_f(acc1[2]); og = sigm(acc1[3]);
        c1 = fg * c1 + ig * gg;
        float h1 = og * tanh_f(c1);

        if (valid) {
            u32 pw = bfbits(h0) | (bfbits(h1) << 16);
            __hip_atomic_store(hist + (long)(s + 1) * 4096 + mm * 256 + (j0 >> 1) + q, pw,
                               __ATOMIC_RELAXED, __HIP_MEMORY_SCOPE_AGENT);
        }
    }
}

// ---------------------------------------------------------------------------
// out[b*T+t] = sigmoid(h_fw[t] . Wfc[:512] + h_bw[t] . Wfc[512:] + bfc)
// hist is u32-packed with the permuted hidden axis: lane reads words
// lane*4 .. +4: word i -> units 8*lane+i (lo16) and 8*lane+4+i (hi16).
// ---------------------------------------------------------------------------
__global__ void final_fc(const u32* __restrict__ hist_fw, const u32* __restrict__ hist_bw,
                         const float* __restrict__ Wfc, const float* __restrict__ bfc,
                         float* __restrict__ out) {
    int gid = blockIdx.x * blockDim.x + threadIdx.x;
    int wid = gid >> 6, lane = gid & 63;
    if (wid >= MROWS) return;
    int b = wid / T_STEPS, t = wid - b * T_STEPS;
    const u32* hf = hist_fw + (long)(t + 1) * 4096 + b * 256 + lane * 4;
    const u32* hb = hist_bw + (long)(T_STEPS - t) * 4096 + b * 256 + lane * 4;
    float s = 0.0f;
#pragma unroll
    for (int i = 0; i < 4; ++i) {
        u32 wf = hf[i], wb = hb[i];
        s += bits2f(wf) * Wfc[8 * lane + i] + bits2f(wf >> 16) * Wfc[8 * lane + 4 + i];
        s += bits2f(wb) * Wfc[512 + 8 * lane + i] + bits2f(wb >> 16) * Wfc[512 + 8 * lane + 4 + i];
    }
#pragma unroll
    for (int off = 32; off > 0; off >>= 1) s += __shfl_down(s, off);
    if (lane == 0) out[wid] = 1.0f / (1.0f + __expf(-(s + bfc[0])));
}

// ---------------------------------------------------------------------------

extern "C" void kernel_launch(void* const* d_in, const int* in_sizes, int n_in,
                              void* d_out, int out_size, void* d_ws, size_t ws_size,
                              hipStream_t stream) {
    const float* x      = (const float*)d_in[0];
    const float* Wdb    = (const float*)d_in[1];
    const float* bdb    = (const float*)d_in[2];
    const float* Wda    = (const float*)d_in[3];
    const float* bda    = (const float*)d_in[4];
    const float* Wr     = (const float*)d_in[5];
    const float* br     = (const float*)d_in[6];
    const float* Wih_fw = (const float*)d_in[7];
    const float* Whh_fw = (const float*)d_in[8];
    const float* bih_fw = (const float*)d_in[9];
    const float* bhh_fw = (const float*)d_in[10];
    const float* Wih_bw = (const float*)d_in[11];
    const float* Whh_bw = (const float*)d_in[12];
    const float* bih_bw = (const float*)d_in[13];
    const float* bhh_bw = (const float*)d_in[14];
    const float* Wfc    = (const float*)d_in[15];
    const float* bfc    = (const float*)d_in[16];
    float* out = (float*)d_out;

    // ---- workspace layout with aliasing (peak ~179.5 MB) ----
    char* p = (char*)d_ws;
    auto alloc = [&](size_t bytes) { char* r = p; p += (bytes + 255) & ~(size_t)255; return r; };
    // persistent region (~46.6 MB): alive until the end
    bf16* Wihc    = (bf16*)alloc((size_t)4096 * 544 * 2);            // 4.5 MB
    bf16* joint   = (bf16*)alloc((size_t)MROWS * 544 * 2);           // 8.8 MB
    u32* hist_fw  = (u32*)alloc((size_t)(T_STEPS + 1) * 4096 * 4);   // 16.6 MB
    u32* hist_bw  = (u32*)alloc((size_t)(T_STEPS + 1) * 4096 * 4);   // 16.6 MB
    // overlay region Q: phase-1 conv buffers, later overwritten by gih
    char* q0 = p;
    bf16* xb      = (bf16*)alloc((size_t)BB * LL * DD * 2);          // 33.6 MB
    bf16* Bdb     = (bf16*)alloc((size_t)512 * 10240 * 2);           // 10.5 MB
    bf16* Bda     = (bf16*)alloc((size_t)512 * 10240 * 2);           // 10.5 MB
    bf16* Br      = (bf16*)alloc((size_t)512 * 20480 * 2);           // 21.0 MB
    float* dbuf   = (float*)alloc((size_t)MROWS * 512 * 4);          // 16.6 MB
    float* dabuf  = (float*)alloc((size_t)MROWS * 512 * 4);          // 16.6 MB
    float* gih    = (float*)q0;  // 132.9 MB, overwrites all of the above
    (void)ws_size;

    cast_x_kernel<<<16384, 256, 0, stream>>>(x, xb, BB * LL * DD / 4);
    prep_convw<<<4096, 256, 0, stream>>>(Wdb, Wda, Wr, Bdb, Bda, Br);
    prep_wihc<<<4096, 256, 0, stream>>>(Wih_fw, bih_fw, bhh_fw, Wih_bw, bih_bw, bhh_bw, Wihc);
    {
        long n4 = (long)(T_STEPS + 1) * 1024 * 2;
        init_kernel<<<(int)((n4 + 255) / 256), 256, 0, stream>>>(hist_fw, hist_bw);
    }

    // db: window [t, t+5);  da: window [t+5, t+10) — fused, 512 blocks (2/CU)
    gemm_bt_dd<<<dim3(64, 4, 2), 256, 0, stream>>>(xb, Bdb, Bda, dbuf, dabuf, bdb, bda);
    // r: window [t, t+10)
    dim3 g1(64, 4);
    gemm_bt<<<g1, 256, 0, stream>>>(xb, Br, joint, br, MROWS, 20480, 1, 0, 0, 544, 1);
    vts_kernel<<<(MROWS * 64 + 255) / 256, 256, 0, stream>>>(dbuf, dabuf, joint);

    // gih GEMM: reads only joint + Wihc; writes gih over the dead conv buffers
    dim3 g2(64, 32);
    gemm_bt<<<g2, 256, 0, stream>>>(joint, Wihc, gih, nullptr, MROWS, 544, 0, 0, 544, 4096, 0);

    lstm_kernel<<<dim3(128), dim3(64), 0, stream>>>(Whh_fw, Whh_bw, gih, hist_fw, hist_bw);

    final_fc<<<(MROWS * 64 + 255) / 256, 256, 0, stream>>>(hist_fw, hist_bw, Wfc, bfc, out);
}

// Round 6
// 4794.285 us; speedup vs baseline: 1.8525x; 1.0227x over previous
//
#include <hip/hip_runtime.h>

// Problem constants (reference: B=8, L=1024, D=2048, H=512, OMEGA=5)
#define BB 8
#define LL 1024
#define DD 2048
#define HHH 512
#define OM 5
#define T_STEPS 1014            // L - 2*OMEGA
#define MROWS (BB * T_STEPS)    // 8112
#define SENT 0xFFFFFFFFu        // bf16 NaN|NaN — unreachable for finite h

typedef __bf16 bf16;
typedef bf16 bf16x8 __attribute__((ext_vector_type(8)));
typedef bf16 bf16x4 __attribute__((ext_vector_type(4)));
typedef float f32x4 __attribute__((ext_vector_type(4)));
typedef unsigned int u32;
typedef unsigned long long u64;
typedef u64 u64x2 __attribute__((ext_vector_type(2)));

__device__ __forceinline__ float sigm(float x) { return 1.0f / (1.0f + __expf(-x)); }
__device__ __forceinline__ float tanh_f(float x) { return 2.0f / (1.0f + __expf(-2.0f * x)) - 1.0f; }
__device__ __forceinline__ u32 bfbits(float x) {
    bf16 b = (bf16)x;
    unsigned short s = __builtin_bit_cast(unsigned short, b);
    return (u32)s;
}
__device__ __forceinline__ float bits2f(u32 v) {
    unsigned short s = (unsigned short)(v & 0xffffu);
    return (float)__builtin_bit_cast(bf16, s);
}
__device__ __forceinline__ u64 al64(const u64* p) {
    return __hip_atomic_load(p, __ATOMIC_RELAXED, __HIP_MEMORY_SCOPE_AGENT);
}
__device__ __forceinline__ bf16x8 quad2frag(u64 lo, u64 hi) {
    u64x2 t; t[0] = lo; t[1] = hi;
    return __builtin_bit_cast(bf16x8, t);
}
__device__ __forceinline__ bool quad_ok(u64 lo, u64 hi) {
    return ((u32)lo != SENT) & ((u32)(lo >> 32) != SENT) &
           ((u32)hi != SENT) & ((u32)(hi >> 32) != SENT);
}

#if defined(__has_builtin)
#if __has_builtin(__builtin_amdgcn_global_load_lds)
#define HAS_GLL 1
#endif
#endif
#ifndef HAS_GLL
#define HAS_GLL 0
#endif

#if HAS_GLL
__device__ __forceinline__ void llds16(const bf16* g, bf16* l) {
    __builtin_amdgcn_global_load_lds((const __attribute__((address_space(1))) void*)g,
                                     (__attribute__((address_space(3))) void*)l, 16, 0, 0);
}
#endif

// ---------------------------------------------------------------------------
// Prep kernels
// ---------------------------------------------------------------------------

__global__ void cast_x_kernel(const float* __restrict__ x, bf16* __restrict__ xb, int n4) {
    int i = blockIdx.x * 256 + threadIdx.x;
    if (i >= n4) return;
    float4 v = ((const float4*)x)[i];
    bf16x4 w = { (bf16)v.x, (bf16)v.y, (bf16)v.z, (bf16)v.w };
    *(bf16x4*)(xb + (long)i * 4) = w;
}

// Wdb/Wda: [H][D][5], Wr: [H][D][10]  ->  B^T layouts [H][K] with k = s*D + d
__global__ void prep_convw(const float* __restrict__ Wdb, const float* __restrict__ Wda,
                           const float* __restrict__ Wr,
                           bf16* __restrict__ Bdb, bf16* __restrict__ Bda, bf16* __restrict__ Br) {
    int idx = blockIdx.x * 256 + threadIdx.x;  // h*2048 + d
    if (idx >= HHH * DD) return;
    int h = idx >> 11, d = idx & 2047;
#pragma unroll
    for (int s = 0; s < 5; ++s) {
        Bdb[(long)h * 10240 + s * DD + d] = (bf16)Wdb[(long)(h * DD + d) * 5 + s];
        Bda[(long)h * 10240 + s * DD + d] = (bf16)Wda[(long)(h * DD + d) * 5 + s];
    }
#pragma unroll
    for (int s = 0; s < 10; ++s) {
        Br[(long)h * 20480 + s * DD + d] = (bf16)Wr[(long)(h * DD + d) * 10 + s];
    }
}

// Wihc: [4096][544]; output col c = dir*2048 + j*4 + g  <- Wih_dir row (g*512+j).
// K rows: 0..511 = Wih[:, :512]; 512 = hi(w512); 513 = hi(w512) (x vts_lo);
// 514 = lo(w512) (x vts_hi); 515 = bias (x 1.0); 516..543 = 0.
__global__ void prep_wihc(const float* __restrict__ Wih_fw, const float* __restrict__ bih_fw,
                          const float* __restrict__ bhh_fw,
                          const float* __restrict__ Wih_bw, const float* __restrict__ bih_bw,
                          const float* __restrict__ bhh_bw, bf16* __restrict__ Wihc) {
    int c = blockIdx.x;
    int tid = threadIdx.x;
    int dir = c >> 11;
    int jg = c & 2047;
    int j = jg >> 2, g = jg & 3;
    int row = g * 512 + j;
    const float* Wih = dir ? Wih_bw : Wih_fw;
    bf16* o = Wihc + (long)c * 544;
    for (int k = tid; k < 512; k += 256) o[k] = (bf16)Wih[(long)row * 513 + k];
    if (tid == 0) {
        float bias = dir ? (bih_bw[row] + bhh_bw[row]) : (bih_fw[row] + bhh_fw[row]);
        float w512 = Wih[(long)row * 513 + 512];
        bf16 hw = (bf16)w512;
        float lw = w512 - (float)hw;
        o[512] = hw; o[513] = hw; o[514] = (bf16)lw; o[515] = (bf16)bias;
    }
    if (tid >= 4 && tid < 32) o[512 + tid] = (bf16)0.0f;  // cols 516..543
}

// hist init: slot 0 = zeros (h_init), slots 1..T = SENT (un-written marker).
// Runs every call (harness re-poisons d_ws with 0xAA).
__global__ void init_kernel(u32* __restrict__ hf, u32* __restrict__ hb) {
    const long n4 = (long)(T_STEPS + 1) * 1024;  // uint4 count per dir
    long i = (long)blockIdx.x * 256 + threadIdx.x;
    if (i >= 2 * n4) return;
    u32* base = (i < n4) ? hf : hb;
    long k = (i < n4) ? i : (i - n4);
    u32 v = (k < 1024) ? 0u : SENT;  // first 1024 uint4 = slot 0
    uint4 val; val.x = v; val.y = v; val.z = v; val.w = v;
    ((uint4*)base)[k] = val;
}

// ---------------------------------------------------------------------------
// GEMM core: C[M][*] = A_win/A_plain (bf16) @ B^T rows (bf16), fp32 accumulate.
// windowed: A row (b,t) = xb + (b*LL + t + shift)*DD  (contiguous im2col-free)
// cmode 0: fp32 store; cmode 1: bf16 store. cbias: per-output-col fp32 bias.
// Staging via global_load_lds width=16 (m97 pattern) when available.
// Shared-memory buffers passed in so multi-branch wrappers keep ONE allocation.
// ---------------------------------------------------------------------------
__device__ __forceinline__
void gemm_core(bf16* Ash, bf16* Bsh,
               const bf16* __restrict__ A, const bf16* __restrict__ Bm, void* __restrict__ Cout,
               const float* __restrict__ cbias, int M, int K, int windowed, int shift,
               int lda, int ldc, int cmode) {
    const int tid = threadIdx.x;
    const int m0 = blockIdx.x * 128;
    const int n0 = blockIdx.y * 128;

    long aoff[2], boff[2];
#pragma unroll
    for (int it = 0; it < 2; ++it) {
        int idx = it * 256 + tid;
        int r = idx & 127, koct = idx >> 7;
        int mg = m0 + r; if (mg >= M) mg = M - 1;
        long abase;
        if (windowed) {
            int b = mg / T_STEPS;
            int t = mg - b * T_STEPS;
            abase = ((long)(b * LL + t + shift)) * DD;
        } else {
            abase = (long)mg * lda;
        }
        aoff[it] = abase + koct * 8;
        boff[it] = (long)(n0 + r) * K + koct * 8;
    }

    const int wave = tid >> 6, lane = tid & 63;
    const int wr = (wave >> 1) * 64;
    const int wc = (wave & 1) * 64;
    const int q = lane >> 4, mm = lane & 15;

    f32x4 acc[4][4] = {};

    for (int k0 = 0; k0 < K; k0 += 32) {
#if HAS_GLL
        __syncthreads();  // protect LDS from overwrite while prior reads active
#pragma unroll
        for (int it = 0; it < 2; ++it) {
            // dst: lane writes (it*256 + wave*64 + lane)*16 bytes (HW: base+lane*16)
            bf16* la = Ash + (size_t)(it * 256 + wave * 64) * 8;
            bf16* lb = Bsh + (size_t)(it * 256 + wave * 64) * 8;
            llds16(A + aoff[it] + k0, la);
            llds16(Bm + boff[it] + k0, lb);
        }
        __syncthreads();  // compiler drains vmcnt(0) before barrier -> LDS ready
#else
        uint4 av[2], bv[2];
#pragma unroll
        for (int it = 0; it < 2; ++it) {
            av[it] = *(const uint4*)(A + aoff[it] + k0);
            bv[it] = *(const uint4*)(Bm + boff[it] + k0);
        }
        __syncthreads();
#pragma unroll
        for (int it = 0; it < 2; ++it) {
            int idx = it * 256 + tid;
            *(uint4*)((char*)Ash + idx * 16) = av[it];
            *(uint4*)((char*)Bsh + idx * 16) = bv[it];
        }
        __syncthreads();
#endif
        bf16x8 af[4], bfr[4];
#pragma unroll
        for (int i = 0; i < 4; ++i) {
            af[i]  = *(const bf16x8*)((char*)Ash + q * 2048 + (wr + i * 16 + mm) * 16);
            bfr[i] = *(const bf16x8*)((char*)Bsh + q * 2048 + (wc + i * 16 + mm) * 16);
        }
#pragma unroll
        for (int i = 0; i < 4; ++i)
#pragma unroll
            for (int j = 0; j < 4; ++j)
                acc[i][j] = __builtin_amdgcn_mfma_f32_16x16x32_bf16(af[i], bfr[j], acc[i][j], 0, 0, 0);
    }

#pragma unroll
    for (int i = 0; i < 4; ++i) {
        int rowb = m0 + wr + i * 16 + q * 4;
#pragma unroll
        for (int j = 0; j < 4; ++j) {
            int col = n0 + wc + j * 16 + mm;
            float bias = cbias ? cbias[col] : 0.0f;
#pragma unroll
            for (int r = 0; r < 4; ++r) {
                int gr = rowb + r;
                if (gr < M) {
                    float v = acc[i][j][r] + bias;
                    if (cmode == 0) ((float*)Cout)[(long)gr * ldc + col] = v;
                    else            ((bf16*)Cout)[(long)gr * ldc + col] = (bf16)v;
                }
            }
        }
    }
}

__global__ __launch_bounds__(256, 2)
void gemm_bt(const bf16* __restrict__ A, const bf16* __restrict__ Bm, void* __restrict__ Cout,
             const float* __restrict__ cbias, int M, int K, int windowed, int shift,
             int lda, int ldc, int cmode) {
    __shared__ bf16 Ash[128 * 32];
    __shared__ bf16 Bsh[128 * 32];
    gemm_core(Ash, Bsh, A, Bm, Cout, cbias, M, K, windowed, shift, lda, ldc, cmode);
}

// All three conv GEMMs fused into one 768-block launch (blockIdx.z selects):
// z=0: db (taps 0..4), z=1: da (taps 5..9), z=2: r (taps 0..9, bf16 store into
// joint). One dispatch packs 2 blocks/CU and pipelines the short (K=10240)
// and long (K=20480) blocks instead of two serialized 1-block/CU waves.
// [R10 measured: db+da fusion alone was −240 µs]
__global__ __launch_bounds__(256, 2)
void gemm_bt_conv(const bf16* __restrict__ A, const bf16* __restrict__ B0,
                  const bf16* __restrict__ B1, const bf16* __restrict__ B2,
                  float* __restrict__ C0, float* __restrict__ C1, bf16* __restrict__ C2,
                  const float* __restrict__ bias0, const float* __restrict__ bias1,
                  const float* __restrict__ bias2) {
    __shared__ bf16 Ash[128 * 32];
    __shared__ bf16 Bsh[128 * 32];
    if (blockIdx.z == 0)
        gemm_core(Ash, Bsh, A, B0, C0, bias0, MROWS, 10240, 1, 0, 0, 512, 0);
    else if (blockIdx.z == 1)
        gemm_core(Ash, Bsh, A, B1, C1, bias1, MROWS, 10240, 1, 5, 0, 512, 0);
    else
        gemm_core(Ash, Bsh, A, B2, C2, bias2, MROWS, 20480, 1, 0, 0, 544, 1);
}

// ---------------------------------------------------------------------------
// vts_d[b,t] = dot(db[b,t,:], da[b,t,:]) -> joint cols 512..543 (hi/lo split + 1.0 + zeros)
// ---------------------------------------------------------------------------
__global__ void vts_kernel(const float* __restrict__ dbuf, const float* __restrict__ dabuf,
                           bf16* __restrict__ joint) {
    int gid = blockIdx.x * blockDim.x + threadIdx.x;
    int wid = gid >> 6, lane = gid & 63;
    if (wid >= MROWS) return;
    const float* p1 = dbuf + (long)wid * 512 + lane * 8;
    const float* p2 = dabuf + (long)wid * 512 + lane * 8;
    float s = 0.0f;
#pragma unroll
    for (int j = 0; j < 8; ++j) s += p1[j] * p2[j];
#pragma unroll
    for (int off = 32; off > 0; off >>= 1) s += __shfl_down(s, off);
    bf16* row = joint + (long)wid * 544;
    if (lane == 0) {
        bf16 hv = (bf16)s;
        float lo = s - (float)hv;
        row[512] = hv; row[513] = (bf16)lo; row[514] = hv; row[515] = (bf16)1.0f;
    }
    if (lane >= 4 && lane < 32) row[512 + lane] = (bf16)0.0f;  // cols 516..543
}

// ---------------------------------------------------------------------------
// Persistent LSTM (R10 form, verified): 128 blocks x 64 threads (64 waves/dir,
// 8 hidden units per wave). Plain launch: 128 one-wave WGs co-resident on the
// idle 256-CU GPU; dataflow sync can't deadlock (monotone).
//
// SENTINEL DATAFLOW SYNC: slots 1..T pre-filled with 0xFFFFFFFF (bf16 NaN
// pair — finite h never produces it). Writers publish h via relaxed agent
// u32 stores; readers poll the h words themselves until != SENT.
//
// R11 LESSON (NaN fail): hist must ONLY be accessed through agent-scope
// (L2-bypassing) ops. L2-scope (sc0) polls allocate stale SENT lines in the
// reader XCD's L2, and downstream plain-load readers (final_fc) then hit
// those stale lines -> NaN. No XCD-local shortcut is sound here.
//
// hist layout per dir (u32-packed, PERMUTED hidden axis): [T+1][16 b][256 u32]
// position p <-> unit (p&~7)+((p&7)>>1)+4*(p&1); same perm on Whh cols & Wfc.
// ---------------------------------------------------------------------------
__global__ __launch_bounds__(64) __attribute__((amdgpu_waves_per_eu(1, 1)))
void lstm_kernel(const float* __restrict__ Whh_fw, const float* __restrict__ Whh_bw,
                 const float* __restrict__ gih, u32* __restrict__ hist_fw,
                 u32* __restrict__ hist_bw) {
    const int wgid = blockIdx.x;
    const int dir = wgid >> 6;
    const int w = wgid & 63;
    const int j0 = w * 8;
    const int lane = threadIdx.x;
    const float* Whh = dir ? Whh_bw : Whh_fw;
    u32* hist = dir ? hist_bw : hist_fw;

    const int q = lane >> 4, mm = lane & 15;

    // Pre-pack A fragments: local rows rl = u*4+g (u=unit, g=gate i/f/g/o),
    // MFMA A layout: lane holds A[m=lane&15][k=(lane>>4)*8 + j].
    // Column j of k-octet (ks,q): permuted position p=ks*32+q*8+j
    // -> Whh column (p&~7) + (j>>1) + 4*(j&1).
    bf16x8 afrag[2][16];
#pragma unroll
    for (int mt = 0; mt < 2; ++mt) {
        int rl = mt * 16 + mm;
        int u = rl >> 2, g = rl & 3;
        const float* wrow = Whh + ((long)(g * 512 + j0 + u)) * 512;
#pragma unroll
        for (int ks = 0; ks < 16; ++ks) {
            int base = ks * 32 + q * 8;
            bf16x8 f;
#pragma unroll
            for (int j = 0; j < 8; ++j) {
                int col = base + (j >> 1) + ((j & 1) << 2);
                f[j] = (bf16)wrow[col];
            }
            afrag[mt][ks] = f;
        }
    }

    float c0 = 0.0f, c1 = 0.0f;
    const bool valid = (mm < 8);
    const int bcl = valid ? mm : 0;  // clamp gih row for pad lanes

    int tcur = dir ? (T_STEPS - 1) : 0;
    const float* gp0 = gih + ((long)(bcl * T_STEPS + tcur)) * 4096 + dir * 2048 + (j0 + q) * 4;
    f32x4 pg0 = *(const f32x4*)gp0;
    f32x4 pg1 = *(const f32x4*)(gp0 + 16);

    for (int s = 0; s < T_STEPS; ++s) {
        const u64* hrow = (const u64*)(hist + (long)s * 4096 + mm * 256);
        // quad ks lives at u64 indices ks*8 + q*2 + {0,1}
        u64 wa[16], wb[16];
#pragma unroll
        for (int i = 0; i < 16; ++i) { wa[i] = 0ull; wb[i] = 0ull; }

        // ---- half 0 (quads 0..7): first-shot issue, then tight spin ----
        u32 pa = valid ? 0xFFu : 0u;
        if (valid) {
#pragma unroll
            for (int ks = 0; ks < 8; ++ks) {
                const u64* p = hrow + ks * 8 + q * 2;
                wa[2 * ks]     = al64(p + 0);
                wa[2 * ks + 1] = al64(p + 1);
            }
        }
        for (;;) {
#pragma unroll
            for (int ks = 0; ks < 8; ++ks) {
                if (pa & (1u << ks)) {
                    if (quad_ok(wa[2 * ks], wa[2 * ks + 1])) pa &= ~(1u << ks);
                }
            }
            if (__all((int)(pa == 0u))) break;
#pragma unroll
            for (int ks = 0; ks < 8; ++ks) {
                if (pa & (1u << ks)) {
                    const u64* p = hrow + ks * 8 + q * 2;
                    wa[2 * ks]     = al64(p + 0);
                    wa[2 * ks + 1] = al64(p + 1);
                }
            }
        }

        // ---- first-shot issue of half 1 (overlaps with half-0 MFMAs) ----
        u32 pb = valid ? 0xFFu : 0u;
        if (valid) {
#pragma unroll
            for (int ks = 0; ks < 8; ++ks) {
                const u64* p = hrow + (ks + 8) * 8 + q * 2;
                wb[2 * ks]     = al64(p + 0);
                wb[2 * ks + 1] = al64(p + 1);
            }
        }

        // C operand = precomputed input gates (bias included, (j*4+g) order)
        f32x4 acc0 = pg0, acc1 = pg1;
        f32x4 acc0b = {0.0f, 0.0f, 0.0f, 0.0f}, acc1b = {0.0f, 0.0f, 0.0f, 0.0f};

        // prefetch gih for next step (hides under the MFMA chain)
        if (s + 1 < T_STEPS) {
            int tn = dir ? (T_STEPS - 2 - s) : (s + 1);
            const float* gpn = gih + ((long)(bcl * T_STEPS + tn)) * 4096 + dir * 2048 + (j0 + q) * 4;
            pg0 = *(const f32x4*)gpn;
            pg1 = *(const f32x4*)(gpn + 16);
        }

        // ---- MFMA half 0 (half-1 loads in flight) ----
#pragma unroll
        for (int ks = 0; ks < 8; ++ks) {
            bf16x8 b = quad2frag(wa[2 * ks], wa[2 * ks + 1]);
            acc0 = __builtin_amdgcn_mfma_f32_16x16x32_bf16(afrag[0][ks], b, acc0, 0, 0, 0);
            acc1 = __builtin_amdgcn_mfma_f32_16x16x32_bf16(afrag[1][ks], b, acc1, 0, 0, 0);
        }

        // ---- finish poll half 1 (tight spin) ----
        for (;;) {
#pragma unroll
            for (int ks = 0; ks < 8; ++ks) {
                if (pb & (1u << ks)) {
                    if (quad_ok(wb[2 * ks], wb[2 * ks + 1])) pb &= ~(1u << ks);
                }
            }
            if (__all((int)(pb == 0u))) break;
#pragma unroll
            for (int ks = 0; ks < 8; ++ks) {
                if (pb & (1u << ks)) {
                    const u64* p = hrow + (ks + 8) * 8 + q * 2;
                    wb[2 * ks]     = al64(p + 0);
                    wb[2 * ks + 1] = al64(p + 1);
                }
            }
        }

        // ---- MFMA half 1 ----
#pragma unroll
        for (int ks = 0; ks < 8; ++ks) {
            bf16x8 b = quad2frag(wb[2 * ks], wb[2 * ks + 1]);
            acc0b = __builtin_amdgcn_mfma_f32_16x16x32_bf16(afrag[0][ks + 8], b, acc0b, 0, 0, 0);
            acc1b = __builtin_amdgcn_mfma_f32_16x16x32_bf16(afrag[1][ks + 8], b, acc1b, 0, 0, 0);
        }
        acc0 += acc0b;
        acc1 += acc1b;

        // D layout: col=lane&15=b, row=(lane>>4)*4+reg -> unit q (+4), gate = reg
        float ig = sigm(acc0[0]), fg = sigm(acc0[1]), gg = tanh_f(acc0[2]), og = sigm(acc0[3]);
        c0 = fg * c0 + ig * gg;
        float h0 = og * tanh_f(c0);
        ig = sigm(acc1[0]); fg = sigm(acc1[1]); gg = tanh_f(acc1[2]); og = sigm(acc1[3]);
        c1 = fg * c1 + ig * gg;
        float h1 = og * tanh_f(c1);

        if (valid) {
            u32 pw = bfbits(h0) | (bfbits(h1) << 16);
            __hip_atomic_store(hist + (long)(s + 1) * 4096 + mm * 256 + (j0 >> 1) + q, pw,
                               __ATOMIC_RELAXED, __HIP_MEMORY_SCOPE_AGENT);
        }
    }
}

// ---------------------------------------------------------------------------
// out[b*T+t] = sigmoid(h_fw[t] . Wfc[:512] + h_bw[t] . Wfc[512:] + bfc)
// hist is u32-packed with the permuted hidden axis: lane reads words
// lane*4 .. +4: word i -> units 8*lane+i (lo16) and 8*lane+4+i (hi16).
// ---------------------------------------------------------------------------
__global__ void final_fc(const u32* __restrict__ hist_fw, const u32* __restrict__ hist_bw,
                         const float* __restrict__ Wfc, const float* __restrict__ bfc,
                         float* __restrict__ out) {
    int gid = blockIdx.x * blockDim.x + threadIdx.x;
    int wid = gid >> 6, lane = gid & 63;
    if (wid >= MROWS) return;
    int b = wid / T_STEPS, t = wid - b * T_STEPS;
    const u32* hf = hist_fw + (long)(t + 1) * 4096 + b * 256 + lane * 4;
    const u32* hb = hist_bw + (long)(T_STEPS - t) * 4096 + b * 256 + lane * 4;
    float s = 0.0f;
#pragma unroll
    for (int i = 0; i < 4; ++i) {
        u32 wf = hf[i], wb = hb[i];
        s += bits2f(wf) * Wfc[8 * lane + i] + bits2f(wf >> 16) * Wfc[8 * lane + 4 + i];
        s += bits2f(wb) * Wfc[512 + 8 * lane + i] + bits2f(wb >> 16) * Wfc[512 + 8 * lane + 4 + i];
    }
#pragma unroll
    for (int off = 32; off > 0; off >>= 1) s += __shfl_down(s, off);
    if (lane == 0) out[wid] = 1.0f / (1.0f + __expf(-(s + bfc[0])));
}

// ---------------------------------------------------------------------------

extern "C" void kernel_launch(void* const* d_in, const int* in_sizes, int n_in,
                              void* d_out, int out_size, void* d_ws, size_t ws_size,
                              hipStream_t stream) {
    const float* x      = (const float*)d_in[0];
    const float* Wdb    = (const float*)d_in[1];
    const float* bdb    = (const float*)d_in[2];
    const float* Wda    = (const float*)d_in[3];
    const float* bda    = (const float*)d_in[4];
    const float* Wr     = (const float*)d_in[5];
    const float* br     = (const float*)d_in[6];
    const float* Wih_fw = (const float*)d_in[7];
    const float* Whh_fw = (const float*)d_in[8];
    const float* bih_fw = (const float*)d_in[9];
    const float* bhh_fw = (const float*)d_in[10];
    const float* Wih_bw = (const float*)d_in[11];
    const float* Whh_bw = (const float*)d_in[12];
    const float* bih_bw = (const float*)d_in[13];
    const float* bhh_bw = (const float*)d_in[14];
    const float* Wfc    = (const float*)d_in[15];
    const float* bfc    = (const float*)d_in[16];
    float* out = (float*)d_out;

    // ---- workspace layout with aliasing (peak ~179.5 MB) ----
    char* p = (char*)d_ws;
    auto alloc = [&](size_t bytes) { char* r = p; p += (bytes + 255) & ~(size_t)255; return r; };
    // persistent region (~46.6 MB): alive until the end
    bf16* Wihc    = (bf16*)alloc((size_t)4096 * 544 * 2);            // 4.5 MB
    bf16* joint   = (bf16*)alloc((size_t)MROWS * 544 * 2);           // 8.8 MB
    u32* hist_fw  = (u32*)alloc((size_t)(T_STEPS + 1) * 4096 * 4);   // 16.6 MB
    u32* hist_bw  = (u32*)alloc((size_t)(T_STEPS + 1) * 4096 * 4);   // 16.6 MB
    // overlay region Q: phase-1 conv buffers, later overwritten by gih
    char* q0 = p;
    bf16* xb      = (bf16*)alloc((size_t)BB * LL * DD * 2);          // 33.6 MB
    bf16* Bdb     = (bf16*)alloc((size_t)512 * 10240 * 2);           // 10.5 MB
    bf16* Bda     = (bf16*)alloc((size_t)512 * 10240 * 2);           // 10.5 MB
    bf16* Br      = (bf16*)alloc((size_t)512 * 20480 * 2);           // 21.0 MB
    float* dbuf   = (float*)alloc((size_t)MROWS * 512 * 4);          // 16.6 MB
    float* dabuf  = (float*)alloc((size_t)MROWS * 512 * 4);          // 16.6 MB
    float* gih    = (float*)q0;  // 132.9 MB, overwrites all of the above
    (void)ws_size;

    cast_x_kernel<<<16384, 256, 0, stream>>>(x, xb, BB * LL * DD / 4);
    prep_convw<<<4096, 256, 0, stream>>>(Wdb, Wda, Wr, Bdb, Bda, Br);
    prep_wihc<<<4096, 256, 0, stream>>>(Wih_fw, bih_fw, bhh_fw, Wih_bw, bih_bw, bhh_bw, Wihc);
    {
        long n4 = (long)(T_STEPS + 1) * 1024 * 2;
        init_kernel<<<(int)((n4 + 255) / 256), 256, 0, stream>>>(hist_fw, hist_bw);
    }

    // db: window [t,t+5); da: [t+5,t+10); r: [t,t+10) — one fused 768-block launch
    gemm_bt_conv<<<dim3(64, 4, 3), 256, 0, stream>>>(xb, Bdb, Bda, Br, dbuf, dabuf, joint,
                                                     bdb, bda, br);
    vts_kernel<<<(MROWS * 64 + 255) / 256, 256, 0, stream>>>(dbuf, dabuf, joint);

    // gih GEMM: reads only joint + Wihc; writes gih over the dead conv buffers
    dim3 g2(64, 32);
    gemm_bt<<<g2, 256, 0, stream>>>(joint, Wihc, gih, nullptr, MROWS, 544, 0, 0, 544, 4096, 0);

    lstm_kernel<<<dim3(128), dim3(64), 0, stream>>>(Whh_fw, Whh_bw, gih, hist_fw, hist_bw);

    final_fc<<<(MROWS * 64 + 255) / 256, 256, 0, stream>>>(hist_fw, hist_bw, Wfc, bfc, out);
}